// Round 2
// baseline (241.756 us; speedup 1.0000x reference)
//
#include <hip/hip_runtime.h>

#define Bn 32
#define Cn 3
#define Hn 512
#define Wn 512
#define HWn (Hn * Wn)

// FOV = 0.3125*512 = 160 exactly; K = 0.208*512 = 106.496
#define FOVc 160.0f
#define Kc   106.496f

// ---------------- Pass 1: per-batch reductions over saliency & r ----------------
// ws layout: ws[b*4 + 0] = sum(S), +1 = sum(S*r), +2 = sum(S*r^2), +3 = max(r) (float bits, atomicMax as int)
// ws[128 + b] = fov_eff, ws[160 + b] = coef   (written by finalize_k)
__global__ __launch_bounds__(256) void reduce_k(const float4* __restrict__ sal,
                                                const float* __restrict__ gaze,
                                                float* __restrict__ ws) {
    const int b = blockIdx.y;
    const float xg = gaze[2 * b + 0];
    const float yg = gaze[2 * b + 1];
    const int tid = threadIdx.x;
    const int idx0 = blockIdx.x * 256 + tid;           // float4 index within batch
    const float4* sb = sal + (size_t)b * (HWn / 4);

    float sumS = 0.0f, sumSr = 0.0f, sumSr2 = 0.0f, rmax = 0.0f;

    for (int i = idx0; i < HWn / 4; i += 16 * 256) {
        float4 s4 = sb[i];
        const int pix = i * 4;
        const float y = (float)(pix >> 9);
        const float xbase = (float)(pix & 511);
        const float dy = y - yg;
        const float dy2 = dy * dy + 1e-6f;
        const float sv[4] = {s4.x, s4.y, s4.z, s4.w};
#pragma unroll
        for (int j = 0; j < 4; ++j) {
            const float dx = xbase + (float)j - xg;
            const float r = sqrtf(dx * dx + dy2);
            const float s = sv[j];
            sumS   += s;
            sumSr  += s * r;
            sumSr2 += s * r * r;
            rmax = fmaxf(rmax, r);
        }
    }

    // wave (64-lane) butterfly reduce
#pragma unroll
    for (int off = 32; off > 0; off >>= 1) {
        sumS   += __shfl_down(sumS, off);
        sumSr  += __shfl_down(sumSr, off);
        sumSr2 += __shfl_down(sumSr2, off);
        rmax = fmaxf(rmax, __shfl_down(rmax, off));
    }

    __shared__ float red[4][4];
    const int wave = tid >> 6, lane = tid & 63;
    if (lane == 0) {
        red[wave][0] = sumS; red[wave][1] = sumSr; red[wave][2] = sumSr2; red[wave][3] = rmax;
    }
    __syncthreads();
    if (tid == 0) {
        float a = 0, c = 0, d = 0, m = 0;
        for (int w = 0; w < 4; ++w) {
            a += red[w][0]; c += red[w][1]; d += red[w][2]; m = fmaxf(m, red[w][3]);
        }
        atomicAdd(&ws[b * 4 + 0], a);
        atomicAdd(&ws[b * 4 + 1], c);
        atomicAdd(&ws[b * 4 + 2], d);
        atomicMax(reinterpret_cast<int*>(&ws[b * 4 + 3]), __float_as_int(m));
    }
}

// ---------------- Pass 2: per-batch scalars ----------------
__global__ void finalize_k(float* __restrict__ ws) {
    const int b = threadIdx.x;
    if (b >= Bn) return;
    const float sumS   = ws[b * 4 + 0];
    const float sumSr  = ws[b * 4 + 1];
    const float sumSr2 = ws[b * 4 + 2];
    const float rmax   = ws[b * 4 + 3];

    const float inv = 1.0f / (sumS + 1e-6f);
    const float mean_r  = sumSr * inv;
    const float mean_r2 = sumSr2 * inv;
    const float var_r = mean_r2 - mean_r * mean_r;
    const float std_r = sqrtf(fmaxf(var_r, 0.0f));
    const float spread = std_r / rmax;
    const float fov_eff = FOVc * (1.0f + 0.5f * spread);

    // r_tfm is monotone nondecreasing in r => max(r_tfm) = r_tfm(rmax)
    float t;
    if (rmax < fov_eff) {
        t = rmax;
    } else {
        const float rk = rmax + Kc;
        t = rk * rk / (2.0f * (fov_eff + Kc)) + (fov_eff - Kc) * 0.5f;
    }
    const float coef = rmax / (t + 1e-6f);

    ws[128 + b] = fov_eff;
    ws[160 + b] = coef;
}

// ---------------- Pass 3: warp + bilinear sample + uint8 truncate ----------------
__global__ __launch_bounds__(256) void sample_k(const float* __restrict__ img,
                                                const float* __restrict__ gaze,
                                                const float* __restrict__ ws,
                                                int* __restrict__ out) {
    const int b = blockIdx.y;
    const int pix = blockIdx.x * 256 + threadIdx.x;

    const float xg = gaze[2 * b + 0];
    const float yg = gaze[2 * b + 1];
    const float fov_eff = ws[128 + b];
    const float coef    = ws[160 + b];

    const float y = (float)(pix >> 9);
    const float x = (float)(pix & 511);
    const float dx = x - xg;
    const float dy = y - yg;
    const float r = sqrtf(dx * dx + dy * dy + 1e-6f);

    const float rk = r + Kc;
    const float r_peri = rk * rk / (2.0f * (fov_eff + Kc)) + (fov_eff - Kc) * 0.5f;
    const float r_tfm = (r < fov_eff) ? r : r_peri;
    const float r_new = coef * r_tfm;
    const float scale = r_new / r;

    const float X = xg + dx * scale;
    const float Y = yg + dy * scale;

    // bilinear with zero padding (mask invalid corners), indices clipped
    const float x0f = floorf(X), y0f = floorf(Y);
    const float x1f = x0f + 1.0f, y1f = y0f + 1.0f;
    const float wx1 = X - x0f, wx0 = 1.0f - wx1;
    const float wy1 = Y - y0f, wy0 = 1.0f - wy1;

    const float m00 = (x0f >= 0.0f && x0f <= 511.0f && y0f >= 0.0f && y0f <= 511.0f) ? 1.0f : 0.0f;
    const float m01 = (x1f >= 0.0f && x1f <= 511.0f && y0f >= 0.0f && y0f <= 511.0f) ? 1.0f : 0.0f;
    const float m10 = (x0f >= 0.0f && x0f <= 511.0f && y1f >= 0.0f && y1f <= 511.0f) ? 1.0f : 0.0f;
    const float m11 = (x1f >= 0.0f && x1f <= 511.0f && y1f >= 0.0f && y1f <= 511.0f) ? 1.0f : 0.0f;

    const int xi0 = (int)fminf(fmaxf(x0f, 0.0f), 511.0f);
    const int xi1 = (int)fminf(fmaxf(x1f, 0.0f), 511.0f);
    const int yi0 = (int)fminf(fmaxf(y0f, 0.0f), 511.0f);
    const int yi1 = (int)fminf(fmaxf(y1f, 0.0f), 511.0f);

    const float w00 = wy0 * wx0 * m00;
    const float w01 = wy0 * wx1 * m01;
    const float w10 = wy1 * wx0 * m10;
    const float w11 = wy1 * wx1 * m11;

    const int o00 = yi0 * Wn + xi0;
    const int o01 = yi0 * Wn + xi1;
    const int o10 = yi1 * Wn + xi0;
    const int o11 = yi1 * Wn + xi1;

    const float* ib = img + (size_t)b * Cn * HWn;
#pragma unroll
    for (int c = 0; c < Cn; ++c) {
        const float* p = ib + (size_t)c * HWn;
        float v = p[o00] * w00 + p[o01] * w01 + p[o10] * w10 + p[o11] * w11;
        v = fminf(fmaxf(v, 0.0f), 255.0f);
        // uint8 truncation; harness reads d_out as int32
        out[((size_t)b * Cn + c) * HWn + pix] = (int)v;
    }
}

extern "C" void kernel_launch(void* const* d_in, const int* in_sizes, int n_in,
                              void* d_out, int out_size, void* d_ws, size_t ws_size,
                              hipStream_t stream) {
    const float* img  = (const float*)d_in[0];
    const float* gaze = (const float*)d_in[1];
    const float* sal  = (const float*)d_in[2];
    int* out  = (int*)d_out;
    float* ws = (float*)d_ws;

    // zero the accumulation area (first 128 floats)
    hipMemsetAsync(d_ws, 0, 128 * sizeof(float), stream);

    reduce_k<<<dim3(16, Bn), 256, 0, stream>>>((const float4*)sal, gaze, ws);
    finalize_k<<<1, 32, 0, stream>>>(ws);
    sample_k<<<dim3(HWn / 256, Bn), 256, 0, stream>>>(img, gaze, ws, out);
}